// Round 5
// baseline (8318.925 us; speedup 1.0000x reference)
//
#include <hip/hip_runtime.h>

#define N_NODES 10242
#define NNZ_E   71694
#define BT      32      // B*T
#define C_IN    16
#define K_S     20
#define C_OUT   32
#define F       512     // BT * C_IN
typedef unsigned short u16;
typedef unsigned int   u32;

#define SLICE_FLOATS ((size_t)N_NODES * 64)   // fp32 elems per 64-col slice
#define BUF_FLOATS   ((size_t)N_NODES * F)    // fp32 T buffer, sliced layout [8][N][64]
#define BUF_BYTES    (BUF_FLOATS * 4)         // ~21 MB
#define PROJ_ELEMS   ((size_t)N_NODES * F)    // bf16 proj copy, layout [N][bt*16+c]
#define PROJ_BYTES   (PROJ_ELEMS * 2)         // ~10.5 MB
#define NGROUPS      ((N_NODES + 3) / 4)      // 2561 groups of 4 nodes

__device__ __forceinline__ float bf2f(u32 h) {
    union { u32 u; float f; } v; v.u = h << 16; return v.f;
}
__device__ __forceinline__ u16 f2bf(float f) {
    union { float f; u32 u; } v; v.f = f;
    u32 r = v.u + 0x7fffu + ((v.u >> 16) & 1u);   // RNE
    return (u16)(r >> 16);
}
__device__ __forceinline__ void unpack8(uint4 u, float* f) {
    f[0] = bf2f(u.x & 0xffffu); f[1] = bf2f(u.x >> 16);
    f[2] = bf2f(u.y & 0xffffu); f[3] = bf2f(u.y >> 16);
    f[4] = bf2f(u.z & 0xffffu); f[5] = bf2f(u.z >> 16);
    f[6] = bf2f(u.w & 0xffffu); f[7] = bf2f(u.w >> 16);
}

// ---------------- CSR build (deterministic) ----------------

__global__ void zero_kernel(int* p, int n) {
    int i = blockIdx.x * blockDim.x + threadIdx.x;
    if (i < n) p[i] = 0;
}

__global__ void count_kernel(const int* __restrict__ erow, int* cnt) {
    int e = blockIdx.x * blockDim.x + threadIdx.x;
    if (e < NNZ_E) atomicAdd(&cnt[erow[e]], 1);
}

__global__ void scan_kernel(const int* __restrict__ cnt, int* row_ptr, int* cursor) {
    const int T = 256;
    const int chunk = (N_NODES + T - 1) / T;  // 41
    __shared__ int part[T];
    int t = threadIdx.x;
    int base = t * chunk;
    int s = 0;
    for (int i = 0; i < chunk; ++i) {
        int idx = base + i;
        if (idx < N_NODES) s += cnt[idx];
    }
    part[t] = s;
    __syncthreads();
    for (int off = 1; off < T; off <<= 1) {
        int v = (t >= off) ? part[t - off] : 0;
        __syncthreads();
        part[t] += v;
        __syncthreads();
    }
    int run = (t == 0) ? 0 : part[t - 1];
    for (int i = 0; i < chunk; ++i) {
        int idx = base + i;
        if (idx < N_NODES) {
            row_ptr[idx] = run;
            cursor[idx]  = run;
            run += cnt[idx];
        }
    }
    if (base <= N_NODES && N_NODES < base + chunk) {
        row_ptr[N_NODES] = run;
    }
}

// scatter ORIGINAL EDGE INDEX (order nondeterministic, fixed by per-row sort)
__global__ void scatter_kernel(const int* __restrict__ erow, int* cursor, int* __restrict__ eidx) {
    int e = blockIdx.x * blockDim.x + threadIdx.x;
    if (e < NNZ_E) {
        int p = atomicAdd(&cursor[erow[e]], 1);
        eidx[p] = e;
    }
}

__global__ void sort_rows_kernel(const int* __restrict__ row_ptr, int* eidx) {
    int r = blockIdx.x * blockDim.x + threadIdx.x;
    if (r >= N_NODES) return;
    int s = row_ptr[r], e = row_ptr[r + 1];
    for (int i = s + 1; i < e; ++i) {
        int key = eidx[i];
        int j = i - 1;
        while (j >= s && eidx[j] > key) { eidx[j + 1] = eidx[j]; --j; }
        eidx[j + 1] = key;
    }
}

// pack (col, val) into int2 for single broadcast load per edge
__global__ void fill_csr_kernel(const int* __restrict__ eidx,
                                const int* __restrict__ ecol, const float* __restrict__ eval,
                                int2* __restrict__ cpack) {
    int p = blockIdx.x * blockDim.x + threadIdx.x;
    if (p < NNZ_E) {
        int e = eidx[p];
        cpack[p] = make_int2(ecol[e], __float_as_int(eval[e]));
    }
}

// Wt[k][c][cout] = W[cout][c*K_S + k]
__global__ void wt_kernel(const float* __restrict__ W, float* __restrict__ Wt) {
    int i = blockIdx.x * blockDim.x + threadIdx.x;  // 10240
    if (i < K_S * C_IN * C_OUT) {
        int cout = i & 31;
        int c    = (i >> 5) & 15;
        int k    = i >> 9;
        Wt[i] = W[cout * (C_IN * K_S) + c * K_S + k];
    }
}

// ---------------- transform: x -> T0 (fp32 sliced) + bf16 proj copy -------
// sliced layout: T[s][n][bt_local*16 + c], bt = s*4 + bt_local

__global__ __launch_bounds__(256) void transform_kernel(
        const float* __restrict__ x, float* __restrict__ T0, u16* __restrict__ proj0) {
    int g = blockIdx.x * 256 + threadIdx.x;   // over N*F elements
    int n    = g >> 9;
    int rem  = g & 511;
    int s    = rem >> 6;
    int lane = rem & 63;
    int bt = s * 4 + (lane >> 4);
    int c  = lane & 15;
    float v = x[((size_t)bt * N_NODES + n) * C_IN + c];
    T0[(size_t)s * SLICE_FLOATS + (size_t)n * 64 + lane] = v;
    proj0[(size_t)n * F + s * 64 + lane] = f2bf(v);
}

// ---------------- Chebyshev step: XCD-local slice processing --------------
// work item = (slice, group-of-4-nodes); claimed via per-slice cursors;
// preferred slice = hardware XCC id, with fallback to other slices so
// correctness never depends on the xcc->dispatch mapping.

__global__ __launch_bounds__(256) void spmm_step_kernel(
        const float* __restrict__ srcB, const float* __restrict__ srcA,
        float* __restrict__ dst, u16* __restrict__ projw,
        const int* __restrict__ row_ptr, const int2* __restrict__ cpack,
        float alpha, float beta, int* __restrict__ cur) {
    int pref;
    asm volatile("s_getreg_b32 %0, hwreg(HW_REG_XCC_ID)" : "=s"(pref));
    pref &= 7;
    __shared__ int sh_grp;
    int w    = threadIdx.x >> 6;
    int lane = threadIdx.x & 63;

    for (int ss = 0; ss < 8; ++ss) {
        int s = (pref + ss) & 7;
        const float* Bs = srcB + (size_t)s * SLICE_FLOATS;
        for (;;) {
            __syncthreads();
            if (threadIdx.x == 0) sh_grp = atomicAdd(&cur[s], 1);
            __syncthreads();
            int grp = sh_grp;
            if (grp >= NGROUPS) break;
            int n = grp * 4 + w;
            if (n < N_NODES) {
                int start = row_ptr[n], end = row_ptr[n + 1];
                float a0 = 0.f, a1 = 0.f, a2 = 0.f, a3 = 0.f;
                int e = start;
                for (; e + 3 < end; e += 4) {
                    int2 p0 = cpack[e],     p1 = cpack[e + 1];
                    int2 p2 = cpack[e + 2], p3 = cpack[e + 3];
                    a0 += __int_as_float(p0.y) * Bs[(size_t)p0.x * 64 + lane];
                    a1 += __int_as_float(p1.y) * Bs[(size_t)p1.x * 64 + lane];
                    a2 += __int_as_float(p2.y) * Bs[(size_t)p2.x * 64 + lane];
                    a3 += __int_as_float(p3.y) * Bs[(size_t)p3.x * 64 + lane];
                }
                for (; e < end; ++e) {
                    int2 p = cpack[e];
                    a0 += __int_as_float(p.y) * Bs[(size_t)p.x * 64 + lane];
                }
                float acc = (a0 + a1) + (a2 + a3);
                size_t off = (size_t)s * SLICE_FLOATS + (size_t)n * 64 + lane;
                float y = alpha * acc;
                if (beta != 0.f) y += beta * srcA[off];
                dst[off] = y;
                projw[(size_t)n * F + s * 64 + lane] = f2bf(y);
            }
        }
    }
}

// ---------------- projection over a chunk of k values ---------------------
// software-pipelined bf16 y loads; out-RMW preloaded before the k loop

__global__ __launch_bounds__(256) void proj_kernel(
        const u16* __restrict__ projbase, int Rbf, int k0, int kcnt,
        const float* __restrict__ Wt, float* __restrict__ out, int accumulate) {
    int g = blockIdx.x * 256 + threadIdx.x;   // over N*BT rows
    if (g >= N_NODES * BT) return;
    int bt = g & 31;
    int n  = g >> 5;
    size_t rowoff = (size_t)n * F + bt * C_IN;
    float* op = out + ((size_t)bt * N_NODES + n) * C_OUT;

    float acc[C_OUT];
    if (accumulate) {
        #pragma unroll
        for (int qq = 0; qq < 8; ++qq)
            *(float4*)(acc + 4 * qq) = *(const float4*)(op + 4 * qq);
    } else {
        #pragma unroll
        for (int co = 0; co < C_OUT; ++co) acc[co] = 0.f;
    }

    const u16* Tr = projbase + (size_t)(k0 % Rbf) * PROJ_ELEMS + rowoff;
    uint4 u0 = ((const uint4*)Tr)[0];
    uint4 u1 = ((const uint4*)Tr)[1];

    for (int j = 0; j < kcnt; ++j) {
        uint4 v0, v1;
        if (j + 1 < kcnt) {
            const u16* Tn = projbase + (size_t)((k0 + j + 1) % Rbf) * PROJ_ELEMS + rowoff;
            v0 = ((const uint4*)Tn)[0];
            v1 = ((const uint4*)Tn)[1];
        }
        float yv[C_IN];
        unpack8(u0, yv); unpack8(u1, yv + 8);
        const float* wk = Wt + (size_t)(k0 + j) * (C_IN * C_OUT);
        #pragma unroll
        for (int c = 0; c < C_IN; ++c) {
            #pragma unroll
            for (int co = 0; co < C_OUT; ++co)
                acc[co] += yv[c] * wk[c * C_OUT + co];
        }
        u0 = v0; u1 = v1;
    }

    #pragma unroll
    for (int qq = 0; qq < 8; ++qq)
        *(float4*)(op + 4 * qq) = *(float4*)(acc + 4 * qq);
}

// ---------------- host launch ----------------

extern "C" void kernel_launch(void* const* d_in, const int* in_sizes, int n_in,
                              void* d_out, int out_size, void* d_ws, size_t ws_size,
                              hipStream_t stream) {
    const float* x    = (const float*)d_in[0];
    const int*   erow = (const int*)  d_in[1];
    const int*   ecol = (const int*)  d_in[2];
    const float* eval = (const float*)d_in[3];
    const float* W    = (const float*)d_in[4];
    float* out = (float*)d_out;

    char* ws = (char*)d_ws;
    size_t o = 0;
    auto alloc = [&](size_t bytes) -> char* {
        o = (o + 511) & ~(size_t)511;
        char* r = ws + o;
        o += bytes;
        return r;
    };
    int*   cnt      = (int*)  alloc((size_t)N_NODES * 4);
    int*   row_ptr  = (int*)  alloc((size_t)(N_NODES + 1) * 4);
    int*   cursor   = (int*)  alloc((size_t)N_NODES * 4);
    int*   eidx     = (int*)  alloc((size_t)NNZ_E * 4);
    int2*  cpack    = (int2*) alloc((size_t)NNZ_E * 8);
    float* Wt       = (float*)alloc((size_t)K_S * C_IN * C_OUT * 4);
    int*   spmm_cur = (int*)  alloc((size_t)(K_S - 1) * 8 * 4);   // 19 steps x 8 slices

    // fp32 recurrence ring: 3 buffers (sliced layout)
    float* fbase = (float*)alloc(3 * BUF_BYTES);
    auto buf = [&](int k) -> float* { return fbase + (size_t)(k % 3) * BUF_FLOATS; };

    // bf16 proj ring sized from remaining workspace
    o = (o + 511) & ~(size_t)511;
    size_t remain = (ws_size > o) ? (ws_size - o) : 0;
    int Rbf = (int)(remain / PROJ_BYTES);
    if (Rbf > K_S) Rbf = K_S;
    if (Rbf < 1)  Rbf = 1;
    u16* projbase = (u16*)alloc((size_t)Rbf * PROJ_BYTES);
    auto projslot = [&](int k) -> u16* { return projbase + (size_t)(k % Rbf) * PROJ_ELEMS; };

    // CSR build (deterministic) + weight transpose + cursor zeroing
    zero_kernel<<<(N_NODES + 255) / 256, 256, 0, stream>>>(cnt, N_NODES);
    zero_kernel<<<1, 256, 0, stream>>>(spmm_cur, (K_S - 1) * 8);
    count_kernel<<<(NNZ_E + 255) / 256, 256, 0, stream>>>(erow, cnt);
    scan_kernel<<<1, 256, 0, stream>>>(cnt, row_ptr, cursor);
    scatter_kernel<<<(NNZ_E + 255) / 256, 256, 0, stream>>>(erow, cursor, eidx);
    sort_rows_kernel<<<(N_NODES + 255) / 256, 256, 0, stream>>>(row_ptr, eidx);
    fill_csr_kernel<<<(NNZ_E + 255) / 256, 256, 0, stream>>>(eidx, ecol, eval, cpack);
    wt_kernel<<<(K_S * C_IN * C_OUT + 255) / 256, 256, 0, stream>>>(W, Wt);

    const int proj_blocks = (N_NODES * BT + 255) / 256;
    int c0 = 0;
    auto maybe_pass = [&](int k_done) {
        int target = K_S - c0;
        if (target > Rbf) target = Rbf;
        if (target > 0 && (k_done - c0 + 1) == target) {
            proj_kernel<<<proj_blocks, 256, 0, stream>>>(
                projbase, Rbf, c0, target, Wt, out, (c0 > 0) ? 1 : 0);
            c0 += target;
        }
    };

    // T0 (N*F/256 = 20484 blocks exactly)
    transform_kernel<<<(int)(BUF_FLOATS / 256), 256, 0, stream>>>(x, buf(0), projslot(0));
    maybe_pass(0);

    // T1 = L T0 ; Tk = 2 L T_{k-1} - T_{k-2}
    for (int k = 1; k < K_S; ++k) {
        const float* srcB = buf(k - 1);
        const float* srcA = (k >= 2) ? buf(k - 2) : buf(k - 1);  // unread when beta==0
        float alpha = (k == 1) ? 1.f : 2.f;
        float beta  = (k == 1) ? 0.f : -1.f;
        spmm_step_kernel<<<2048, 256, 0, stream>>>(
            srcB, srcA, buf(k), projslot(k), row_ptr, cpack, alpha, beta,
            spmm_cur + (size_t)(k - 1) * 8);
        maybe_pass(k);
    }
}

// Round 6
// 754.213 us; speedup vs baseline: 11.0299x; 11.0299x over previous
//
#include <hip/hip_runtime.h>

#define N_NODES 10242
#define NNZ_E   71694
#define NNZ_PAD_MAX (NNZ_E + 3 * N_NODES)   // rows padded to multiple of 4
#define BT      32      // B*T
#define C_IN    16
#define K_S     20
#define C_OUT   32
#define F       512     // BT * C_IN
typedef unsigned short u16;
typedef unsigned int   u32;

#define BUF_FLOATS ((size_t)N_NODES * F)    // fp32 T buffer, layout [n][bt*16+c]
#define BUF_BYTES  (BUF_FLOATS * 4)         // ~21 MB
#define PROJ_ELEMS ((size_t)N_NODES * F)    // bf16 proj copy, layout [n][bt*16+c]
#define PROJ_BYTES (PROJ_ELEMS * 2)         // ~10.5 MB

typedef __attribute__((ext_vector_type(8)))  short short8;
typedef __attribute__((ext_vector_type(16))) float float16;

__device__ __forceinline__ u16 f2bf(float f) {
    union { float f; u32 u; } v; v.f = f;
    u32 r = v.u + 0x7fffu + ((v.u >> 16) & 1u);   // RNE
    return (u16)(r >> 16);
}

// ---------------- CSR build (deterministic, rows padded to x4) -------------

__global__ void zero_kernel(int* p, int n) {
    int i = blockIdx.x * blockDim.x + threadIdx.x;
    if (i < n) p[i] = 0;
}

__global__ void count_kernel(const int* __restrict__ erow, int* cnt) {
    int e = blockIdx.x * blockDim.x + threadIdx.x;
    if (e < NNZ_E) atomicAdd(&cnt[erow[e]], 1);
}

// exclusive scan of PADDED counts -> row_ptr; cursor = row_ptr (claims fill real slots)
__global__ void scan_kernel(const int* __restrict__ cnt, int* row_ptr, int* cursor) {
    const int T = 256;
    const int chunk = (N_NODES + T - 1) / T;  // 41
    __shared__ int part[T];
    int t = threadIdx.x;
    int base = t * chunk;
    int s = 0;
    for (int i = 0; i < chunk; ++i) {
        int idx = base + i;
        if (idx < N_NODES) s += (cnt[idx] + 3) & ~3;
    }
    part[t] = s;
    __syncthreads();
    for (int off = 1; off < T; off <<= 1) {
        int v = (t >= off) ? part[t - off] : 0;
        __syncthreads();
        part[t] += v;
        __syncthreads();
    }
    int run = (t == 0) ? 0 : part[t - 1];
    for (int i = 0; i < chunk; ++i) {
        int idx = base + i;
        if (idx < N_NODES) {
            row_ptr[idx] = run;
            cursor[idx]  = run;
            run += (cnt[idx] + 3) & ~3;
        }
    }
    if (base <= N_NODES && N_NODES < base + chunk) {
        row_ptr[N_NODES] = run;
    }
}

// scatter ORIGINAL EDGE INDEX (order nondeterministic, fixed by per-row sort)
__global__ void scatter_kernel(const int* __restrict__ erow, int* cursor, int* __restrict__ eidx) {
    int e = blockIdx.x * blockDim.x + threadIdx.x;
    if (e < NNZ_E) {
        int p = atomicAdd(&cursor[erow[e]], 1);
        eidx[p] = e;
    }
}

__global__ void sort_rows_kernel(const int* __restrict__ row_ptr, const int* __restrict__ cnt,
                                 int* eidx) {
    int r = blockIdx.x * blockDim.x + threadIdx.x;
    if (r >= N_NODES) return;
    int s = row_ptr[r], e = s + cnt[r];
    for (int i = s + 1; i < e; ++i) {
        int key = eidx[i];
        int j = i - 1;
        while (j >= s && eidx[j] > key) { eidx[j + 1] = eidx[j]; --j; }
        eidx[j + 1] = key;
    }
}

// fill real edges as packed (col, val); pad slots stay (0, 0.0f) from pre-zero
__global__ void fill_csr_kernel(const int* __restrict__ row_ptr, const int* __restrict__ cnt,
                                const int* __restrict__ eidx,
                                const int* __restrict__ ecol, const float* __restrict__ eval,
                                int2* __restrict__ cpack) {
    int r = blockIdx.x * blockDim.x + threadIdx.x;
    if (r >= N_NODES) return;
    int s = row_ptr[r], e = s + cnt[r];
    for (int p = s; p < e; ++p) {
        int ed = eidx[p];
        cpack[p] = make_int2(ecol[ed], __float_as_int(eval[ed]));
    }
}

// B-fragments for v_mfma_f32_32x32x16_bf16, per k_cheb:
// lane L, reg j  ->  B[k = 8*(L>>5)+j][col = L&31] = W[cout=col][c=k][k_cheb]
// stored wtfrag[k_cheb][L*8 + j] (bf16), so a lane loads 16B at L*16.
__global__ void wtfrag_kernel(const float* __restrict__ W, u16* __restrict__ wtfrag) {
    int i = blockIdx.x * blockDim.x + threadIdx.x;  // K_S*64*8 = 10240
    if (i >= K_S * 64 * 8) return;
    int j    = i & 7;
    int lane = (i >> 3) & 63;
    int k    = i >> 9;
    int cout = lane & 31;
    int c    = ((lane >> 5) << 3) + j;
    wtfrag[i] = f2bf(W[cout * (C_IN * K_S) + c * K_S + k]);
}

// ---------------- transform: x -> T0 (fp32) + bf16 proj copy --------------
// T layout: T[n][bt*16 + c]

__global__ __launch_bounds__(256) void transform_kernel(
        const float* __restrict__ x, float* __restrict__ T0, u16* __restrict__ proj0) {
    int g = blockIdx.x * 256 + threadIdx.x;   // over N*F
    int n   = g >> 9;
    int rem = g & 511;
    int bt  = rem >> 4;
    int c   = rem & 15;
    float v = x[((size_t)bt * N_NODES + n) * C_IN + c];
    T0[(size_t)n * F + rem] = v;
    proj0[(size_t)n * F + rem] = f2bf(v);
}

// ---------------- Chebyshev step: wave-per-node, padded 4-edge batches -----
// dst = alpha * L @ srcB + beta * srcA ; projw = bf16(dst)

__global__ __launch_bounds__(64) void spmm_step_kernel(
        const float* __restrict__ srcB, const float* __restrict__ srcA,
        float* __restrict__ dst, u16* __restrict__ projw,
        const int* __restrict__ row_ptr, const int2* __restrict__ cpack,
        float alpha, float beta) {
    int n = blockIdx.x;                   // block-uniform -> scalar loads
    int lane = threadIdx.x;
    int s = row_ptr[n], e_end = row_ptr[n + 1];   // padded count, multiple of 4
    int o1 = lane * 4;                    // first half of the 512-float row
    int o2 = 256 + lane * 4;              // second half

    float4 aa0 = {0,0,0,0}, ab0 = {0,0,0,0};
    float4 aa1 = {0,0,0,0}, ab1 = {0,0,0,0};

    for (int e = s; e < e_end; e += 4) {
        int2 p0 = cpack[e + 0], p1 = cpack[e + 1];
        int2 p2 = cpack[e + 2], p3 = cpack[e + 3];
        const float* r0 = srcB + (size_t)p0.x * F;
        const float* r1 = srcB + (size_t)p1.x * F;
        const float* r2 = srcB + (size_t)p2.x * F;
        const float* r3 = srcB + (size_t)p3.x * F;
        float4 b0a = *(const float4*)(r0 + o1), b0b = *(const float4*)(r0 + o2);
        float4 b1a = *(const float4*)(r1 + o1), b1b = *(const float4*)(r1 + o2);
        float4 b2a = *(const float4*)(r2 + o1), b2b = *(const float4*)(r2 + o2);
        float4 b3a = *(const float4*)(r3 + o1), b3b = *(const float4*)(r3 + o2);
        float v0 = __int_as_float(p0.y), v1 = __int_as_float(p1.y);
        float v2 = __int_as_float(p2.y), v3 = __int_as_float(p3.y);
        aa0.x += v0 * b0a.x; aa0.y += v0 * b0a.y; aa0.z += v0 * b0a.z; aa0.w += v0 * b0a.w;
        ab0.x += v0 * b0b.x; ab0.y += v0 * b0b.y; ab0.z += v0 * b0b.z; ab0.w += v0 * b0b.w;
        aa1.x += v1 * b1a.x; aa1.y += v1 * b1a.y; aa1.z += v1 * b1a.z; aa1.w += v1 * b1a.w;
        ab1.x += v1 * b1b.x; ab1.y += v1 * b1b.y; ab1.z += v1 * b1b.z; ab1.w += v1 * b1b.w;
        aa0.x += v2 * b2a.x; aa0.y += v2 * b2a.y; aa0.z += v2 * b2a.z; aa0.w += v2 * b2a.w;
        ab0.x += v2 * b2b.x; ab0.y += v2 * b2b.y; ab0.z += v2 * b2b.z; ab0.w += v2 * b2b.w;
        aa1.x += v3 * b3a.x; aa1.y += v3 * b3a.y; aa1.z += v3 * b3a.z; aa1.w += v3 * b3a.w;
        ab1.x += v3 * b3b.x; ab1.y += v3 * b3b.y; ab1.z += v3 * b3b.z; ab1.w += v3 * b3b.w;
    }

    float ya[4] = { alpha * (aa0.x + aa1.x), alpha * (aa0.y + aa1.y),
                    alpha * (aa0.z + aa1.z), alpha * (aa0.w + aa1.w) };
    float yb[4] = { alpha * (ab0.x + ab1.x), alpha * (ab0.y + ab1.y),
                    alpha * (ab0.z + ab1.z), alpha * (ab0.w + ab1.w) };
    if (beta != 0.f) {
        float4 sa = *(const float4*)(srcA + (size_t)n * F + o1);
        float4 sb = *(const float4*)(srcA + (size_t)n * F + o2);
        ya[0] += beta * sa.x; ya[1] += beta * sa.y; ya[2] += beta * sa.z; ya[3] += beta * sa.w;
        yb[0] += beta * sb.x; yb[1] += beta * sb.y; yb[2] += beta * sb.z; yb[3] += beta * sb.w;
    }
    *(float4*)(dst + (size_t)n * F + o1) = *(float4*)ya;
    *(float4*)(dst + (size_t)n * F + o2) = *(float4*)yb;

    u16* pw = projw + (size_t)n * F;
    uint2 pa, pb;
    pa.x = (u32)f2bf(ya[0]) | ((u32)f2bf(ya[1]) << 16);
    pa.y = (u32)f2bf(ya[2]) | ((u32)f2bf(ya[3]) << 16);
    pb.x = (u32)f2bf(yb[0]) | ((u32)f2bf(yb[1]) << 16);
    pb.y = (u32)f2bf(yb[2]) | ((u32)f2bf(yb[3]) << 16);
    *(uint2*)(pw + o1) = pa;
    *(uint2*)(pw + o2) = pb;
}

// ---------------- MFMA projection over a chunk of k values ----------------
// per wave: one node n; tile M=32 (bt rows) x N=32 (cout), K = kcnt*16.
// A[m][kk] = proj_k[n][m*16 + kk]  (m=bt, kk=c)  -> lane: m=L&31, kk=8*(L>>5)+j
// B from precomputed wtfrag. C/D: col=L&31, row=(reg&3)+8*(reg>>2)+4*(L>>5).

__global__ __launch_bounds__(256) void proj_mfma_kernel(
        const u16* __restrict__ projbase, int Rbf, int k0, int kcnt,
        const u16* __restrict__ wtfrag, float* __restrict__ out, int accumulate) {
    int wave = threadIdx.x >> 6;
    int lane = threadIdx.x & 63;
    int n = blockIdx.x * 4 + wave;
    if (n >= N_NODES) return;   // wave-uniform exit

    int col = lane & 31;
    int grp = lane >> 5;

    float16 acc = {};
    for (int j = 0; j < kcnt; ++j) {
        int k = k0 + j;
        const u16* Ab = projbase + (size_t)(k % Rbf) * PROJ_ELEMS + (size_t)n * F
                      + (size_t)col * 16 + grp * 8;
        const u16* Bb = wtfrag + (size_t)k * 512 + lane * 8;
        union { uint4 u; short8 s; } av, bv;
        av.u = *(const uint4*)Ab;
        bv.u = *(const uint4*)Bb;
        acc = __builtin_amdgcn_mfma_f32_32x32x16_bf16(av.s, bv.s, acc, 0, 0, 0);
    }

    #pragma unroll
    for (int r = 0; r < 16; ++r) {
        int bt = (r & 3) + 8 * (r >> 2) + 4 * grp;
        float* op = out + ((size_t)bt * N_NODES + n) * C_OUT + col;
        if (accumulate) *op += acc[r];
        else            *op  = acc[r];
    }
}

// ---------------- host launch ----------------

extern "C" void kernel_launch(void* const* d_in, const int* in_sizes, int n_in,
                              void* d_out, int out_size, void* d_ws, size_t ws_size,
                              hipStream_t stream) {
    const float* x    = (const float*)d_in[0];
    const int*   erow = (const int*)  d_in[1];
    const int*   ecol = (const int*)  d_in[2];
    const float* eval = (const float*)d_in[3];
    const float* W    = (const float*)d_in[4];
    float* out = (float*)d_out;

    char* ws = (char*)d_ws;
    size_t o = 0;
    auto alloc = [&](size_t bytes) -> char* {
        o = (o + 511) & ~(size_t)511;
        char* r = ws + o;
        o += bytes;
        return r;
    };
    int*   cnt     = (int*)  alloc((size_t)N_NODES * 4);
    int*   row_ptr = (int*)  alloc((size_t)(N_NODES + 1) * 4);
    int*   cursor  = (int*)  alloc((size_t)N_NODES * 4);
    int*   eidx    = (int*)  alloc((size_t)NNZ_PAD_MAX * 4);
    int2*  cpack   = (int2*) alloc((size_t)NNZ_PAD_MAX * 8);
    u16*   wtfrag  = (u16*)  alloc((size_t)K_S * 512 * 2);

    // fp32 recurrence ring: 3 buffers
    float* fbase = (float*)alloc(3 * BUF_BYTES);
    auto buf = [&](int k) -> float* { return fbase + (size_t)(k % 3) * BUF_FLOATS; };

    // bf16 proj ring sized from remaining workspace
    o = (o + 511) & ~(size_t)511;
    size_t remain = (ws_size > o) ? (ws_size - o) : 0;
    int Rbf = (int)(remain / PROJ_BYTES);
    if (Rbf > K_S) Rbf = K_S;
    if (Rbf < 1)  Rbf = 1;
    u16* projbase = (u16*)alloc((size_t)Rbf * PROJ_BYTES);
    auto projslot = [&](int k) -> u16* { return projbase + (size_t)(k % Rbf) * PROJ_ELEMS; };

    // CSR build (deterministic, padded) + weight fragments
    zero_kernel<<<(N_NODES + 255) / 256, 256, 0, stream>>>(cnt, N_NODES);
    zero_kernel<<<(2 * NNZ_PAD_MAX + 255) / 256, 256, 0, stream>>>((int*)cpack, 2 * NNZ_PAD_MAX);
    count_kernel<<<(NNZ_E + 255) / 256, 256, 0, stream>>>(erow, cnt);
    scan_kernel<<<1, 256, 0, stream>>>(cnt, row_ptr, cursor);
    scatter_kernel<<<(NNZ_E + 255) / 256, 256, 0, stream>>>(erow, cursor, eidx);
    sort_rows_kernel<<<(N_NODES + 255) / 256, 256, 0, stream>>>(row_ptr, cnt, eidx);
    fill_csr_kernel<<<(N_NODES + 255) / 256, 256, 0, stream>>>(row_ptr, cnt, eidx, ecol, eval, cpack);
    wtfrag_kernel<<<(K_S * 512 + 255) / 256, 256, 0, stream>>>(W, wtfrag);

    const int proj_blocks = (N_NODES + 3) / 4;
    int c0 = 0;
    auto maybe_pass = [&](int k_done) {
        int target = K_S - c0;
        if (target > Rbf) target = Rbf;
        if (target > 0 && (k_done - c0 + 1) == target) {
            proj_mfma_kernel<<<proj_blocks, 256, 0, stream>>>(
                projbase, Rbf, c0, target, wtfrag, out, (c0 > 0) ? 1 : 0);
            c0 += target;
        }
    };

    // T0
    transform_kernel<<<(int)(BUF_FLOATS / 256), 256, 0, stream>>>(x, buf(0), projslot(0));
    maybe_pass(0);

    // T1 = L T0 ; Tk = 2 L T_{k-1} - T_{k-2}
    for (int k = 1; k < K_S; ++k) {
        const float* srcB = buf(k - 1);
        const float* srcA = (k >= 2) ? buf(k - 2) : buf(k - 1);  // unread when beta==0
        float alpha = (k == 1) ? 1.f : 2.f;
        float beta  = (k == 1) ? 0.f : -1.f;
        spmm_step_kernel<<<N_NODES, 64, 0, stream>>>(
            srcB, srcA, buf(k), projslot(k), row_ptr, cpack, alpha, beta);
        maybe_pass(k);
    }
}